// Round 4
// baseline (862.758 us; speedup 1.0000x reference)
//
#include <hip/hip_runtime.h>
#include <hip/hip_bf16.h>

#define B_SZ 8192
#define D_SZ 4096   // K
#define H_SZ 2048
#define N4H  8192   // 4*H = N (gate-interleaved n' space)
#define NT   (D_SZ / 64)   // 64 K-tiles of BK=64

typedef __attribute__((ext_vector_type(8))) __bf16 bf16x8;
typedef __attribute__((ext_vector_type(4))) float f32x4;

#define GPTR(p) ((__attribute__((address_space(1))) void*)(p))
#define LPTR(p) ((__attribute__((address_space(3))) void*)(p))

// ---------------------------------------------------------------------------
// 1) prep: [blocks 0..2047]    combine = bf16(input + hidden)
//    [blocks 2048..34815]      WT[n'][k] = bf16(W_g[k][h]),
//                              n' = (h>>4)*64 + g*16 + (h&15)   (gate-interleave)
// ---------------------------------------------------------------------------
__global__ void prep_k(const float* __restrict__ x, const float* __restrict__ h,
                       __hip_bfloat16* __restrict__ comb,
                       const float* __restrict__ Wf, const float* __restrict__ Wc,
                       const float* __restrict__ Wi, const float* __restrict__ Wo,
                       __hip_bfloat16* __restrict__ WT) {
    __shared__ float t[32][33];
    if (blockIdx.x < 2048) {
        const size_t n4 = (size_t)B_SZ * D_SZ / 4;
        const size_t stride = (size_t)2048 * 256;
        for (size_t i = (size_t)blockIdx.x * 256 + threadIdx.x; i < n4; i += stride) {
            f32x4 a = __builtin_nontemporal_load((const f32x4*)x + i);
            f32x4 b = __builtin_nontemporal_load((const f32x4*)h + i);
            short4 r;
            r.x = __builtin_bit_cast(short, __float2bfloat16(a.x + b.x));
            r.y = __builtin_bit_cast(short, __float2bfloat16(a.y + b.y));
            r.z = __builtin_bit_cast(short, __float2bfloat16(a.z + b.z));
            r.w = __builtin_bit_cast(short, __float2bfloat16(a.w + b.w));
            ((short4*)comb)[i] = r;
        }
    } else {
        const int b = blockIdx.x - 2048;      // 0..32767
        const int k0 = (b & 127) * 32;        // K block
        const int n0 = (b >> 7) * 32;         // old-layout n block (g*2048 + h)
        const float* W = (n0 < H_SZ) ? Wf : (n0 < 2 * H_SZ) ? Wc
                       : (n0 < 3 * H_SZ) ? Wi : Wo;
        const int g = n0 >> 11;
        const int nc = n0 & (H_SZ - 1);
        const int tx = threadIdx.x & 31, ty = threadIdx.x >> 5;
#pragma unroll
        for (int j = 0; j < 4; ++j)
            t[ty + j * 8][tx] = __builtin_nontemporal_load(
                W + (size_t)(k0 + ty + j * 8) * H_SZ + nc + tx);
        __syncthreads();
#pragma unroll
        for (int j = 0; j < 4; ++j) {
            const int h2 = nc + ty + j * 8;                       // h index
            const int np = ((h2 >> 4) << 6) + (g << 4) + (h2 & 15);
            WT[(size_t)np * D_SZ + k0 + tx] = __float2bfloat16(t[tx][ty + j * 8]);
        }
    }
}

// ---------------------------------------------------------------------------
// 2) Persistent GEMM + fused LSTM epilogue.
//    256x256 tile, BK=64, 8 waves (2Mx4N), 8-phase schedule (T1+T2+T3/T4+T5).
//    Grid = 256 blocks; block (xcd=b&7, slot=b>>3) keeps n0 = slot*256 FIXED
//    and iterates works m0 = (xcd*4+it)*256, it = 0..3.
//    Wrap-staging: tiles 62/63 of work it stage tiles 0/1 of work it+1 into
//    the regions they free (parity continuous, NT even) -> the vmcnt(6)
//    invariant carries across works and the pipeline never drains. The LSTM
//    epilogue runs at the work boundary, hidden under in-flight prefetch.
// ---------------------------------------------------------------------------

#define BAR()                                    \
    do {                                         \
        asm volatile("" ::: "memory");           \
        __builtin_amdgcn_s_barrier();            \
        asm volatile("" ::: "memory");           \
    } while (0)

#define STAGE(pbase, HSTRIDE, h, kt, region)                                           \
    do {                                                                               \
        __builtin_amdgcn_global_load_lds(                                              \
            GPTR((pbase) + (size_t)((h) * (HSTRIDE)) * D_SZ + (size_t)(kt) * 64),      \
            LPTR(smem + (region) + (h) * 16384 + wave * 1024), 16, 0, 0);              \
        __builtin_amdgcn_global_load_lds(                                              \
            GPTR((pbase) + (size_t)(128 + (h) * (HSTRIDE)) * D_SZ + (size_t)(kt) * 64),\
            LPTR(smem + (region) + (h) * 16384 + 8192 + wave * 1024), 16, 0, 0);       \
    } while (0)

#define LDA(dst, base, qm)                                                             \
    do {                                                                               \
        _Pragma("unroll") for (int mi = 0; mi < 4; ++mi) {                             \
            const int row_ = (qm) * 128 + wr * 64 + mi * 16 + fr;                      \
            dst[mi][0] = *(const bf16x8*)(smem + (base) + row_ * 128 + sw0);           \
            dst[mi][1] = *(const bf16x8*)(smem + (base) + row_ * 128 + sw1);           \
        }                                                                              \
    } while (0)

#define LDB(dst, base, qn)                                                             \
    do {                                                                               \
        _Pragma("unroll") for (int nf = 0; nf < 2; ++nf) {                             \
            const int row_ = (qn) * 128 + wc * 32 + nf * 16 + fr;                      \
            dst[nf][0] = *(const bf16x8*)(smem + (base) + row_ * 128 + sw0);           \
            dst[nf][1] = *(const bf16x8*)(smem + (base) + row_ * 128 + sw1);           \
        }                                                                              \
    } while (0)

#define MFMA_Q(qm, qn, areg, breg)                                                     \
    do {                                                                               \
        _Pragma("unroll") for (int mi = 0; mi < 4; ++mi)                               \
        _Pragma("unroll") for (int nf = 0; nf < 2; ++nf)                               \
        _Pragma("unroll") for (int ks = 0; ks < 2; ++ks)                               \
            acc[(qm) * 4 + mi][(qn) * 2 + nf] =                                        \
                __builtin_amdgcn_mfma_f32_16x16x32_bf16(                               \
                    areg[mi][ks], breg[nf][ks],                                        \
                    acc[(qm) * 4 + mi][(qn) * 2 + nf], 0, 0, 0);                       \
    } while (0)

// Uniform tile: ALWAYS stages B1(next1 = t+1 wrap) and A0/B0/A1(next2 = t+2
// wrap, pointer PA2 = current or next work's A). vmcnt(6) before the final
// barrier keeps exactly [A0,B0,A1](t+2) in flight (tile t+1 fully landed).
#define TILE_FULL(CA, CB, OB, PA2, K1, K2)                                             \
    {                                                                                  \
        LDA(a, CA, 0);                                                                 \
        LDB(b0, CB, 0);                                                                \
        STAGE(pB, 32, 1, (K1), OB);                                                    \
        BAR();                                                                         \
        asm volatile("s_waitcnt lgkmcnt(0)" ::: "memory");                             \
        __builtin_amdgcn_s_setprio(1);                                                 \
        MFMA_Q(0, 0, a, b0);                                                           \
        __builtin_amdgcn_s_setprio(0);                                                 \
        BAR();                                                                         \
        LDB(b1, CB, 1);                                                                \
        STAGE(PA2, 64, 0, (K2), CA);                                                   \
        BAR();                                                                         \
        asm volatile("s_waitcnt lgkmcnt(0)" ::: "memory");                             \
        __builtin_amdgcn_s_setprio(1);                                                 \
        MFMA_Q(0, 1, a, b1);                                                           \
        __builtin_amdgcn_s_setprio(0);                                                 \
        BAR();                                                                         \
        LDA(a, CA, 1);                                                                 \
        STAGE(pB, 32, 0, (K2), CB);                                                    \
        BAR();                                                                         \
        asm volatile("s_waitcnt lgkmcnt(0)" ::: "memory");                             \
        __builtin_amdgcn_s_setprio(1);                                                 \
        MFMA_Q(1, 0, a, b0);                                                           \
        __builtin_amdgcn_s_setprio(0);                                                 \
        BAR();                                                                         \
        STAGE(PA2, 64, 1, (K2), CA);                                                   \
        BAR();                                                                         \
        __builtin_amdgcn_s_setprio(1);                                                 \
        MFMA_Q(1, 1, a, b1);                                                           \
        __builtin_amdgcn_s_setprio(0);                                                 \
        asm volatile("s_waitcnt vmcnt(6)" ::: "memory");                               \
        BAR();                                                                         \
    }

// Tail tile (final work only): round-3 guarded variant.
#define TILE_TAIL(tcur, CA, CB, OB)                                                    \
    {                                                                                  \
        LDA(a, CA, 0);                                                                 \
        LDB(b0, CB, 0);                                                                \
        if ((tcur) + 1 < NT) STAGE(pB, 32, 1, (tcur) + 1, OB);                         \
        BAR();                                                                         \
        asm volatile("s_waitcnt lgkmcnt(0)" ::: "memory");                             \
        __builtin_amdgcn_s_setprio(1);                                                 \
        MFMA_Q(0, 0, a, b0);                                                           \
        __builtin_amdgcn_s_setprio(0);                                                 \
        BAR();                                                                         \
        LDB(b1, CB, 1);                                                                \
        BAR();                                                                         \
        asm volatile("s_waitcnt lgkmcnt(0)" ::: "memory");                             \
        __builtin_amdgcn_s_setprio(1);                                                 \
        MFMA_Q(0, 1, a, b1);                                                           \
        __builtin_amdgcn_s_setprio(0);                                                 \
        BAR();                                                                         \
        LDA(a, CA, 1);                                                                 \
        BAR();                                                                         \
        asm volatile("s_waitcnt lgkmcnt(0)" ::: "memory");                             \
        __builtin_amdgcn_s_setprio(1);                                                 \
        MFMA_Q(1, 0, a, b0);                                                           \
        __builtin_amdgcn_s_setprio(0);                                                 \
        BAR();                                                                         \
        BAR();                                                                         \
        __builtin_amdgcn_s_setprio(1);                                                 \
        MFMA_Q(1, 1, a, b1);                                                           \
        __builtin_amdgcn_s_setprio(0);                                                 \
        if ((tcur) + 1 < NT) {                                                         \
            asm volatile("s_waitcnt vmcnt(0)" ::: "memory");                           \
        }                                                                              \
        BAR();                                                                         \
    }

__device__ __forceinline__ float fsig(float x) { return 1.f / (1.f + __expf(-x)); }
__device__ __forceinline__ float ftanh(float x) {
    x = fminf(fmaxf(x, -15.f), 15.f);
    float e = __expf(2.f * x);
    return (e - 1.f) / (e + 1.f);
}

__global__ __launch_bounds__(512, 2) void gemm8_k(
    const __hip_bfloat16* __restrict__ A,   // comb [8192][4096]
    const __hip_bfloat16* __restrict__ BT,  // WT   [8192][4096] (gate-interleaved rows)
    const float* __restrict__ cell,         // [8192][2048]
    const float* __restrict__ bfb, const float* __restrict__ bcb,
    const float* __restrict__ bib, const float* __restrict__ bob,
    float* __restrict__ out)                // [out | hid | cst], each [8192][2048]
{
    extern __shared__ char smem[];

    const int tid  = threadIdx.x;
    const int wave = tid >> 6;
    const int lane = tid & 63;
    const int wr = wave >> 2;   // 0..1
    const int wc = wave & 3;    // 0..3
    const int fr = lane & 15;
    const int sw0 = (((lane >> 4) + 0) ^ (fr & 7)) << 4;
    const int sw1 = (((lane >> 4) + 4) ^ (fr & 7)) << 4;

    // persistent mapping: fixed n-column per block, 4 m-works
    const int xcd  = blockIdx.x & 7;
    const int slot = blockIdx.x >> 3;       // 0..31
    const int n0 = slot * 256;

    const int r0   = tid >> 3;
    const int col0 = ((tid & 7) ^ (r0 & 7)) << 3;
    const __hip_bfloat16* pB =
        BT + (size_t)(n0 + ((r0 >> 5) << 6) + (r0 & 31)) * D_SZ + col0;

    const __hip_bfloat16* pA =
        A + (size_t)(xcd * 1024 + r0) * D_SZ + col0;            // work it=0
    const __hip_bfloat16* pA_nx = pA + (size_t)256 * D_SZ;      // work it=1

    // epilogue invariants (n fixed per block)
    const int crow = (lane >> 4) * 4;
    const int ccol = lane & 15;
    const int hh = (slot * 4 + wc) * 16 + ccol;                 // h index
    const float bf_ = bfb[hh], bc_ = bcb[hh], bi_ = bib[hh], bo_ = bob[hh];
    const size_t BH = (size_t)B_SZ * H_SZ;
    float* hidp = out + BH;
    float* cstp = out + 2 * BH;

    f32x4 acc[8][4] = {};
    bf16x8 a[4][2], b0[2][2], b1[2][2];

    // prologue: tile0 -> buf0, tile1 A0,B0,A1 -> buf1 (invariant established)
    STAGE(pA, 64, 0, 0, 0);
    STAGE(pB, 32, 0, 0, 32768);
    STAGE(pA, 64, 1, 0, 0);
    STAGE(pB, 32, 1, 0, 32768);
    STAGE(pA, 64, 0, 1, 65536);
    STAGE(pB, 32, 0, 1, 98304);
    STAGE(pA, 64, 1, 1, 65536);
    asm volatile("s_waitcnt vmcnt(6)" ::: "memory");
    BAR();

#pragma unroll 1
    for (int it = 0; it < 4; ++it) {
        // steady tiles 0..61 (no wrap inside)
#pragma unroll 1
        for (int t = 0; t < 62; t += 2) {
            TILE_FULL(0,     32768, 98304, pA, t + 1, t + 2);
            TILE_FULL(65536, 98304, 32768, pA, t + 2, t + 3);
        }
        // boundary tiles 62,63: stage next work's tiles 0,1 (or tail-drain)
        if (it < 3) {
            TILE_FULL(0,     32768, 98304, pA_nx, 63, 0);
            TILE_FULL(65536, 98304, 32768, pA_nx, 0, 1);
        } else {
            TILE_TAIL(62, 0,     32768, 98304);
            TILE_TAIL(63, 65536, 98304, 32768);
        }

        // ---- fused LSTM epilogue for work `it` (no LDS; hides under prefetch)
        const int m0w = (xcd * 4 + it) * 256;
#pragma unroll
        for (int ai = 0; ai < 8; ++ai) {
#pragma unroll
            for (int j = 0; j < 4; ++j) {
                const size_t r = (size_t)(m0w + wr * 128 + ai * 16 + crow + j);
                const size_t idx = r * H_SZ + hh;
                const float gf = acc[ai][0][j] + bf_;
                const float gc = acc[ai][1][j] + bc_;
                const float gi = acc[ai][2][j] + bi_;
                const float go = acc[ai][3][j] + bo_;
                const float ft = fsig(gf);
                const float ct = ftanh(gc);
                const float it_ = fsig(fsig(gi));   // double sigmoid, faithful
                const float ot = fsig(go);
                const float cv = __builtin_nontemporal_load(cell + idx);
                const float cs = cv * ft + ct * it_;
                __builtin_nontemporal_store(ot, out + idx);
                __builtin_nontemporal_store(cs, cstp + idx);
                __builtin_nontemporal_store(ot * ftanh(cs), hidp + idx);
            }
        }
        // reset accumulators for next work
        if (it < 3) {
#pragma unroll
            for (int ai = 0; ai < 8; ++ai)
#pragma unroll
                for (int bj = 0; bj < 4; ++bj)
                    acc[ai][bj] = (f32x4){0.f, 0.f, 0.f, 0.f};
        }
        pA = pA_nx;
        pA_nx += (size_t)256 * D_SZ;
    }
}

// ---------------------------------------------------------------------------
extern "C" void kernel_launch(void* const* d_in, const int* in_sizes, int n_in,
                              void* d_out, int out_size, void* d_ws, size_t ws_size,
                              hipStream_t stream) {
    const float* input  = (const float*)d_in[0];
    const float* hidden = (const float*)d_in[1];
    const float* cell   = (const float*)d_in[2];
    const float* Wf     = (const float*)d_in[3];
    const float* bfb    = (const float*)d_in[4];
    const float* Wc     = (const float*)d_in[5];
    const float* bcb    = (const float*)d_in[6];
    const float* Wi     = (const float*)d_in[7];
    const float* bib    = (const float*)d_in[8];
    const float* Wo     = (const float*)d_in[9];
    const float* bob    = (const float*)d_in[10];
    float* out = (float*)d_out;

    char* ws = (char*)d_ws;
    __hip_bfloat16* comb = (__hip_bfloat16*)ws;                              // 64 MiB
    __hip_bfloat16* WT   = (__hip_bfloat16*)(ws + (size_t)B_SZ * D_SZ * 2);  // 64 MiB

    hipFuncSetAttribute(reinterpret_cast<const void*>(gemm8_k),
                        hipFuncAttributeMaxDynamicSharedMemorySize, 131072);

    prep_k<<<2048 + 32768, 256, 0, stream>>>(input, hidden, comb, Wf, Wc, Wi, Wo, WT);
    gemm8_k<<<256, 512, 131072, stream>>>(comb, WT, cell, bfb, bcb, bib, bob, out);
}

// Round 5
// 618.351 us; speedup vs baseline: 1.3953x; 1.3953x over previous
//
#include <hip/hip_runtime.h>
#include <hip/hip_bf16.h>

#define B_SZ 8192
#define D_SZ 4096   // K
#define H_SZ 2048
#define N4H  8192   // 4*H = N (gate-interleaved n' space)
#define NT   (D_SZ / 64)   // 64 K-tiles of BK=64
#define ANX  ((size_t)256 * D_SZ)   // A advance per work (256 rows)

typedef __attribute__((ext_vector_type(8))) __bf16 bf16x8;
typedef __attribute__((ext_vector_type(4))) float f32x4;

#define GPTR(p) ((__attribute__((address_space(1))) void*)(p))
#define LPTR(p) ((__attribute__((address_space(3))) void*)(p))

// ---------------------------------------------------------------------------
// 1) prep: [blocks 0..2047]    combine = bf16(input + hidden)
//    [blocks 2048..34815]      WT[n'][k] = bf16(W_g[k][h]),
//                              n' = (h>>4)*64 + g*16 + (h&15)   (gate-interleave)
// ---------------------------------------------------------------------------
__global__ void prep_k(const float* __restrict__ x, const float* __restrict__ h,
                       __hip_bfloat16* __restrict__ comb,
                       const float* __restrict__ Wf, const float* __restrict__ Wc,
                       const float* __restrict__ Wi, const float* __restrict__ Wo,
                       __hip_bfloat16* __restrict__ WT) {
    __shared__ float t[32][33];
    if (blockIdx.x < 2048) {
        const size_t n4 = (size_t)B_SZ * D_SZ / 4;
        const size_t stride = (size_t)2048 * 256;
        for (size_t i = (size_t)blockIdx.x * 256 + threadIdx.x; i < n4; i += stride) {
            f32x4 a = __builtin_nontemporal_load((const f32x4*)x + i);
            f32x4 b = __builtin_nontemporal_load((const f32x4*)h + i);
            short4 r;
            r.x = __builtin_bit_cast(short, __float2bfloat16(a.x + b.x));
            r.y = __builtin_bit_cast(short, __float2bfloat16(a.y + b.y));
            r.z = __builtin_bit_cast(short, __float2bfloat16(a.z + b.z));
            r.w = __builtin_bit_cast(short, __float2bfloat16(a.w + b.w));
            ((short4*)comb)[i] = r;
        }
    } else {
        const int b = blockIdx.x - 2048;      // 0..32767
        const int k0 = (b & 127) * 32;        // K block
        const int n0 = (b >> 7) * 32;         // old-layout n block (g*2048 + h)
        const float* W = (n0 < H_SZ) ? Wf : (n0 < 2 * H_SZ) ? Wc
                       : (n0 < 3 * H_SZ) ? Wi : Wo;
        const int g = n0 >> 11;
        const int nc = n0 & (H_SZ - 1);
        const int tx = threadIdx.x & 31, ty = threadIdx.x >> 5;
#pragma unroll
        for (int j = 0; j < 4; ++j)
            t[ty + j * 8][tx] = __builtin_nontemporal_load(
                W + (size_t)(k0 + ty + j * 8) * H_SZ + nc + tx);
        __syncthreads();
#pragma unroll
        for (int j = 0; j < 4; ++j) {
            const int h2 = nc + ty + j * 8;                       // h index
            const int np = ((h2 >> 4) << 6) + (g << 4) + (h2 & 15);
            WT[(size_t)np * D_SZ + k0 + tx] = __float2bfloat16(t[tx][ty + j * 8]);
        }
    }
}

// ---------------------------------------------------------------------------
// 2) Persistent GEMM + fused LSTM epilogue (v2: register-relieved).
//    256x256 tile, BK=64, 8 waves (2Mx4N), 8-phase schedule (T1+T2+T3/T4+T5).
//    Grid = 256; block (xcd=b&7, slot=b>>3) keeps n0=slot*256 FIXED, iterates
//    works m0 = (xcd*4+it)*256. Wrap-staging keeps the vmcnt(6) invariant
//    across works; boundary tiles of the LAST work prefetch pA+ANX, which for
//    xcd=7 reads the WT workspace region (valid memory, data unused).
//    Unified-reg budget: 8 waves/block -> hard cap 256/wave; epilogue state is
//    scoped inside the it-loop so the K-loop's live set stays ~232.
// ---------------------------------------------------------------------------

#define BAR()                                    \
    do {                                         \
        asm volatile("" ::: "memory");           \
        __builtin_amdgcn_s_barrier();            \
        asm volatile("" ::: "memory");           \
    } while (0)

#define STAGE(pbase, HSTRIDE, h, kt, region)                                           \
    do {                                                                               \
        __builtin_amdgcn_global_load_lds(                                              \
            GPTR((pbase) + (size_t)((h) * (HSTRIDE)) * D_SZ + (size_t)(kt) * 64),      \
            LPTR(smem + (region) + (h) * 16384 + wave * 1024), 16, 0, 0);              \
        __builtin_amdgcn_global_load_lds(                                              \
            GPTR((pbase) + (size_t)(128 + (h) * (HSTRIDE)) * D_SZ + (size_t)(kt) * 64),\
            LPTR(smem + (region) + (h) * 16384 + 8192 + wave * 1024), 16, 0, 0);       \
    } while (0)

#define LDA(dst, base, qm)                                                             \
    do {                                                                               \
        _Pragma("unroll") for (int mi = 0; mi < 4; ++mi) {                             \
            const int row_ = (qm) * 128 + wr * 64 + mi * 16 + fr;                      \
            dst[mi][0] = *(const bf16x8*)(smem + (base) + row_ * 128 + sw0);           \
            dst[mi][1] = *(const bf16x8*)(smem + (base) + row_ * 128 + sw1);           \
        }                                                                              \
    } while (0)

#define LDB(dst, base, qn)                                                             \
    do {                                                                               \
        _Pragma("unroll") for (int nf = 0; nf < 2; ++nf) {                             \
            const int row_ = (qn) * 128 + wc * 32 + nf * 16 + fr;                      \
            dst[nf][0] = *(const bf16x8*)(smem + (base) + row_ * 128 + sw0);           \
            dst[nf][1] = *(const bf16x8*)(smem + (base) + row_ * 128 + sw1);           \
        }                                                                              \
    } while (0)

#define MFMA_Q(qm, qn, areg, breg)                                                     \
    do {                                                                               \
        _Pragma("unroll") for (int mi = 0; mi < 4; ++mi)                               \
        _Pragma("unroll") for (int nf = 0; nf < 2; ++nf)                               \
        _Pragma("unroll") for (int ks = 0; ks < 2; ++ks)                               \
            acc[(qm) * 4 + mi][(qn) * 2 + nf] =                                        \
                __builtin_amdgcn_mfma_f32_16x16x32_bf16(                               \
                    areg[mi][ks], breg[nf][ks],                                        \
                    acc[(qm) * 4 + mi][(qn) * 2 + nf], 0, 0, 0);                       \
    } while (0)

// Uniform tile: stages B1(K1) into OB and A0/B0/A1(K2) into CA/CB (PA2 = A
// pointer for the K2 tile's work). vmcnt(6) before the final barrier keeps
// exactly [A0,B0,A1](t+2) in flight, i.e. tile t+1 fully landed.
#define TILE_FULL(CA, CB, OB, PA2, K1, K2)                                             \
    {                                                                                  \
        LDA(a, CA, 0);                                                                 \
        LDB(b0, CB, 0);                                                                \
        STAGE(pB, 32, 1, (K1), OB);                                                    \
        BAR();                                                                         \
        asm volatile("s_waitcnt lgkmcnt(0)" ::: "memory");                             \
        __builtin_amdgcn_s_setprio(1);                                                 \
        MFMA_Q(0, 0, a, b0);                                                           \
        __builtin_amdgcn_s_setprio(0);                                                 \
        BAR();                                                                         \
        LDB(b1, CB, 1);                                                                \
        STAGE(PA2, 64, 0, (K2), CA);                                                   \
        BAR();                                                                         \
        asm volatile("s_waitcnt lgkmcnt(0)" ::: "memory");                             \
        __builtin_amdgcn_s_setprio(1);                                                 \
        MFMA_Q(0, 1, a, b1);                                                           \
        __builtin_amdgcn_s_setprio(0);                                                 \
        BAR();                                                                         \
        LDA(a, CA, 1);                                                                 \
        STAGE(pB, 32, 0, (K2), CB);                                                    \
        BAR();                                                                         \
        asm volatile("s_waitcnt lgkmcnt(0)" ::: "memory");                             \
        __builtin_amdgcn_s_setprio(1);                                                 \
        MFMA_Q(1, 0, a, b0);                                                           \
        __builtin_amdgcn_s_setprio(0);                                                 \
        BAR();                                                                         \
        STAGE(PA2, 64, 1, (K2), CA);                                                   \
        BAR();                                                                         \
        __builtin_amdgcn_s_setprio(1);                                                 \
        MFMA_Q(1, 1, a, b1);                                                           \
        __builtin_amdgcn_s_setprio(0);                                                 \
        asm volatile("s_waitcnt vmcnt(6)" ::: "memory");                               \
        BAR();                                                                         \
    }

__device__ __forceinline__ float fsig(float x) { return 1.f / (1.f + __expf(-x)); }
__device__ __forceinline__ float ftanh(float x) {
    x = fminf(fmaxf(x, -15.f), 15.f);
    float e = __expf(2.f * x);
    return (e - 1.f) / (e + 1.f);
}

__global__ __launch_bounds__(512, 2) void gemm8_k(
    const __hip_bfloat16* __restrict__ A,   // comb [8192][4096]
    const __hip_bfloat16* __restrict__ BT,  // WT   [8192][4096] (gate-interleaved rows)
    const float* __restrict__ cell,         // [8192][2048]
    const float* __restrict__ bfb, const float* __restrict__ bcb,
    const float* __restrict__ bib, const float* __restrict__ bob,
    float* __restrict__ out)                // [out | hid | cst], each [8192][2048]
{
    extern __shared__ char smem[];

    const int tid  = threadIdx.x;
    const int wave = tid >> 6;
    const int lane = tid & 63;
    const int wr = wave >> 2;   // 0..1
    const int wc = wave & 3;    // 0..3
    const int fr = lane & 15;
    const int sw0 = (((lane >> 4) + 0) ^ (fr & 7)) << 4;
    const int sw1 = (((lane >> 4) + 4) ^ (fr & 7)) << 4;

    // persistent mapping: fixed n-column per block, 4 m-works
    const int r0   = tid >> 3;
    const int col0 = ((tid & 7) ^ (r0 & 7)) << 3;
    const __hip_bfloat16* pB =
        BT + (size_t)((blockIdx.x >> 3) * 256 + ((r0 >> 5) << 6) + (r0 & 31)) * D_SZ + col0;
    const __hip_bfloat16* pA =
        A + (size_t)((blockIdx.x & 7) * 1024 + r0) * D_SZ + col0;   // work it=0

    f32x4 acc[8][4] = {};
    bf16x8 a[4][2], b0[2][2], b1[2][2];

    // prologue: tile0 -> buf0, tile1 A0,B0,A1 -> buf1 (invariant established)
    STAGE(pA, 64, 0, 0, 0);
    STAGE(pB, 32, 0, 0, 32768);
    STAGE(pA, 64, 1, 0, 0);
    STAGE(pB, 32, 1, 0, 32768);
    STAGE(pA, 64, 0, 1, 65536);
    STAGE(pB, 32, 0, 1, 98304);
    STAGE(pA, 64, 1, 1, 65536);
    asm volatile("s_waitcnt vmcnt(6)" ::: "memory");
    BAR();

#pragma unroll 1
    for (int it = 0; it < 4; ++it) {
        // steady tiles 0..61 (no wrap inside)
#pragma unroll 1
        for (int t = 0; t < 62; t += 2) {
            TILE_FULL(0,     32768, 98304, pA, t + 1, t + 2);
            TILE_FULL(65536, 98304, 32768, pA, t + 2, t + 3);
        }
        // boundary tiles 62,63: stage next work's tiles 0,1 (it=3 wraps into
        // the WT workspace region — valid memory, data unused)
        TILE_FULL(0,     32768, 98304, pA + ANX, 63, 0);
        TILE_FULL(65536, 98304, 32768, pA + ANX, 0, 1);

        // ---- fused LSTM epilogue for work `it` (all state scoped here so the
        // K-loop's register live-set stays under the 256/wave cap)
        {
            const int crow = (lane >> 4) * 4;
            const int ccol = lane & 15;
            const int hh = ((blockIdx.x >> 3) * 4 + wc) * 16 + ccol;
            const float bf_ = bfb[hh], bc_ = bcb[hh], bi_ = bib[hh], bo_ = bob[hh];
            const size_t BH = (size_t)B_SZ * H_SZ;
            float* hidp = out + BH;
            float* cstp = out + 2 * BH;
            const int m0w = ((blockIdx.x & 7) * 4 + it) * 256;
#pragma unroll
            for (int ai = 0; ai < 8; ++ai) {
#pragma unroll
                for (int j = 0; j < 4; ++j) {
                    const size_t r = (size_t)(m0w + wr * 128 + ai * 16 + crow + j);
                    const size_t idx = r * H_SZ + hh;
                    const float gf = acc[ai][0][j] + bf_;
                    const float gc = acc[ai][1][j] + bc_;
                    const float gi = acc[ai][2][j] + bi_;
                    const float go = acc[ai][3][j] + bo_;
                    const float ft = fsig(gf);
                    const float ct = ftanh(gc);
                    const float it_ = fsig(fsig(gi));   // double sigmoid, faithful
                    const float ot = fsig(go);
                    const float cv = __builtin_nontemporal_load(cell + idx);
                    const float cs = cv * ft + ct * it_;
                    __builtin_nontemporal_store(ot, out + idx);
                    __builtin_nontemporal_store(cs, cstp + idx);
                    __builtin_nontemporal_store(ot * ftanh(cs), hidp + idx);
                }
            }
        }
        // reset accumulators (unconditional — last one is harmless)
#pragma unroll
        for (int ai = 0; ai < 8; ++ai)
#pragma unroll
            for (int bj = 0; bj < 4; ++bj)
                acc[ai][bj] = (f32x4){0.f, 0.f, 0.f, 0.f};
        pA += ANX;
    }

    // drain pending LDS-DMA (wrap prefetch of the last work) before endpgm
    asm volatile("s_waitcnt vmcnt(0)" ::: "memory");
}

// ---------------------------------------------------------------------------
extern "C" void kernel_launch(void* const* d_in, const int* in_sizes, int n_in,
                              void* d_out, int out_size, void* d_ws, size_t ws_size,
                              hipStream_t stream) {
    const float* input  = (const float*)d_in[0];
    const float* hidden = (const float*)d_in[1];
    const float* cell   = (const float*)d_in[2];
    const float* Wf     = (const float*)d_in[3];
    const float* bfb    = (const float*)d_in[4];
    const float* Wc     = (const float*)d_in[5];
    const float* bcb    = (const float*)d_in[6];
    const float* Wi     = (const float*)d_in[7];
    const float* bib    = (const float*)d_in[8];
    const float* Wo     = (const float*)d_in[9];
    const float* bob    = (const float*)d_in[10];
    float* out = (float*)d_out;

    char* ws = (char*)d_ws;
    __hip_bfloat16* comb = (__hip_bfloat16*)ws;                              // 64 MiB
    __hip_bfloat16* WT   = (__hip_bfloat16*)(ws + (size_t)B_SZ * D_SZ * 2);  // 64 MiB

    hipFuncSetAttribute(reinterpret_cast<const void*>(gemm8_k),
                        hipFuncAttributeMaxDynamicSharedMemorySize, 131072);

    prep_k<<<2048 + 32768, 256, 0, stream>>>(input, hidden, comb, Wf, Wc, Wi, Wo, WT);
    gemm8_k<<<256, 512, 131072, stream>>>(comb, WT, cell, bfb, bcb, bib, bob, out);
}

// Round 6
// 606.149 us; speedup vs baseline: 1.4233x; 1.0201x over previous
//
#include <hip/hip_runtime.h>
#include <hip/hip_bf16.h>

#define B_SZ 8192
#define D_SZ 4096   // K
#define H_SZ 2048
#define N4H  8192   // 4*H = N (gate-interleaved n' space)
#define NT   (D_SZ / 64)   // 64 K-tiles of BK=64
#define ANX  ((size_t)256 * D_SZ)   // A advance per work (256 rows)

typedef __attribute__((ext_vector_type(8))) __bf16 bf16x8;
typedef __attribute__((ext_vector_type(4))) float f32x4;

#define GPTR(p) ((__attribute__((address_space(1))) void*)(p))
#define LPTR(p) ((__attribute__((address_space(3))) void*)(p))

// ---------------------------------------------------------------------------
// 1) prep: [blocks 0..2047]    combine = bf16(input + hidden)
//    [blocks 2048..34815]      WT[n'][k] = bf16(W_g[k][h]),
//                              n' = (h>>4)*64 + g*16 + (h&15)   (gate-interleave)
// ---------------------------------------------------------------------------
__global__ void prep_k(const float* __restrict__ x, const float* __restrict__ h,
                       __hip_bfloat16* __restrict__ comb,
                       const float* __restrict__ Wf, const float* __restrict__ Wc,
                       const float* __restrict__ Wi, const float* __restrict__ Wo,
                       __hip_bfloat16* __restrict__ WT) {
    __shared__ float t[32][33];
    if (blockIdx.x < 2048) {
        const size_t n4 = (size_t)B_SZ * D_SZ / 4;
        const size_t stride = (size_t)2048 * 256;
        for (size_t i = (size_t)blockIdx.x * 256 + threadIdx.x; i < n4; i += stride) {
            f32x4 a = __builtin_nontemporal_load((const f32x4*)x + i);
            f32x4 b = __builtin_nontemporal_load((const f32x4*)h + i);
            short4 r;
            r.x = __builtin_bit_cast(short, __float2bfloat16(a.x + b.x));
            r.y = __builtin_bit_cast(short, __float2bfloat16(a.y + b.y));
            r.z = __builtin_bit_cast(short, __float2bfloat16(a.z + b.z));
            r.w = __builtin_bit_cast(short, __float2bfloat16(a.w + b.w));
            ((short4*)comb)[i] = r;
        }
    } else {
        const int b = blockIdx.x - 2048;      // 0..32767
        const int k0 = (b & 127) * 32;        // K block
        const int n0 = (b >> 7) * 32;         // old-layout n block (g*2048 + h)
        const float* W = (n0 < H_SZ) ? Wf : (n0 < 2 * H_SZ) ? Wc
                       : (n0 < 3 * H_SZ) ? Wi : Wo;
        const int g = n0 >> 11;
        const int nc = n0 & (H_SZ - 1);
        const int tx = threadIdx.x & 31, ty = threadIdx.x >> 5;
#pragma unroll
        for (int j = 0; j < 4; ++j)
            t[ty + j * 8][tx] = __builtin_nontemporal_load(
                W + (size_t)(k0 + ty + j * 8) * H_SZ + nc + tx);
        __syncthreads();
#pragma unroll
        for (int j = 0; j < 4; ++j) {
            const int h2 = nc + ty + j * 8;                       // h index
            const int np = ((h2 >> 4) << 6) + (g << 4) + (h2 & 15);
            WT[(size_t)np * D_SZ + k0 + tx] = __float2bfloat16(t[tx][ty + j * 8]);
        }
    }
}

// ---------------------------------------------------------------------------
// 2) Persistent GEMM + fused LSTM epilogue (v3: single barrier per phase).
//    256x256 tile, BK=64, 8 waves (2Mx4N), 8-phase schedule.
//    Hazard audit for 1-bar/phase: every STAGE's target region had its last
//    ds_read in an earlier phase, and that phase ends lgkmcnt(0) -> MFMA ->
//    BAR, so any wave past that BAR has proof all waves' reads of the region
//    completed (skew bounded to one phase body by the barrier). The vmcnt(6)
//    landing invariant (newest 3 STAGEs in flight, tile t+1 landed at end of
//    tile t) is per-wave and unchanged. Removing bar#1 lets a wave sit in
//    lgkmcnt(0) while its SIMD-partner runs MFMA -> LDS pipe and MFMA pipe
//    overlap across waves instead of serializing in global lockstep.
// ---------------------------------------------------------------------------

#define BAR()                                    \
    do {                                         \
        asm volatile("" ::: "memory");           \
        __builtin_amdgcn_s_barrier();            \
        asm volatile("" ::: "memory");           \
    } while (0)

#define STAGE(pbase, HSTRIDE, h, kt, region)                                           \
    do {                                                                               \
        __builtin_amdgcn_global_load_lds(                                              \
            GPTR((pbase) + (size_t)((h) * (HSTRIDE)) * D_SZ + (size_t)(kt) * 64),      \
            LPTR(smem + (region) + (h) * 16384 + wave * 1024), 16, 0, 0);              \
        __builtin_amdgcn_global_load_lds(                                              \
            GPTR((pbase) + (size_t)(128 + (h) * (HSTRIDE)) * D_SZ + (size_t)(kt) * 64),\
            LPTR(smem + (region) + (h) * 16384 + 8192 + wave * 1024), 16, 0, 0);       \
    } while (0)

#define LDA(dst, base, qm)                                                             \
    do {                                                                               \
        _Pragma("unroll") for (int mi = 0; mi < 4; ++mi) {                             \
            const int row_ = (qm) * 128 + wr * 64 + mi * 16 + fr;                      \
            dst[mi][0] = *(const bf16x8*)(smem + (base) + row_ * 128 + sw0);           \
            dst[mi][1] = *(const bf16x8*)(smem + (base) + row_ * 128 + sw1);           \
        }                                                                              \
    } while (0)

#define LDB(dst, base, qn)                                                             \
    do {                                                                               \
        _Pragma("unroll") for (int nf = 0; nf < 2; ++nf) {                             \
            const int row_ = (qn) * 128 + wc * 32 + nf * 16 + fr;                      \
            dst[nf][0] = *(const bf16x8*)(smem + (base) + row_ * 128 + sw0);           \
            dst[nf][1] = *(const bf16x8*)(smem + (base) + row_ * 128 + sw1);           \
        }                                                                              \
    } while (0)

#define MFMA_Q(qm, qn, areg, breg)                                                     \
    do {                                                                               \
        _Pragma("unroll") for (int mi = 0; mi < 4; ++mi)                               \
        _Pragma("unroll") for (int nf = 0; nf < 2; ++nf)                               \
        _Pragma("unroll") for (int ks = 0; ks < 2; ++ks)                               \
            acc[(qm) * 4 + mi][(qn) * 2 + nf] =                                        \
                __builtin_amdgcn_mfma_f32_16x16x32_bf16(                               \
                    areg[mi][ks], breg[nf][ks],                                        \
                    acc[(qm) * 4 + mi][(qn) * 2 + nf], 0, 0, 0);                       \
    } while (0)

// One K-tile, 4 phases, ONE barrier per phase (after MFMA). STAGE targets:
// ph1 -> B1(K1) into OB (last read: t-1 ph2, >=1 BAR ago); ph2 -> A0(K2) into
// CA rows 0-127 (last read: ph1, drained by ph1's lgkm0 before its BAR);
// ph3 -> B0(K2) into CB rows 0-127 (last read ph1, 2 BARs ago); ph4 -> A1(K2)
// into CA rows 128-255 (last read ph3, drained before ph3's BAR). vmcnt(6)
// before the final BAR => tile t+1 fully landed, newest 3 STAGEs in flight.
#define TILE_FULL(CA, CB, OB, PA2, K1, K2)                                             \
    {                                                                                  \
        LDA(a, CA, 0);                                                                 \
        LDB(b0, CB, 0);                                                                \
        STAGE(pB, 32, 1, (K1), OB);                                                    \
        asm volatile("s_waitcnt lgkmcnt(0)" ::: "memory");                             \
        __builtin_amdgcn_s_setprio(1);                                                 \
        MFMA_Q(0, 0, a, b0);                                                           \
        __builtin_amdgcn_s_setprio(0);                                                 \
        BAR();                                                                         \
        LDB(b1, CB, 1);                                                                \
        STAGE(PA2, 64, 0, (K2), CA);                                                   \
        asm volatile("s_waitcnt lgkmcnt(0)" ::: "memory");                             \
        __builtin_amdgcn_s_setprio(1);                                                 \
        MFMA_Q(0, 1, a, b1);                                                           \
        __builtin_amdgcn_s_setprio(0);                                                 \
        BAR();                                                                         \
        LDA(a, CA, 1);                                                                 \
        STAGE(pB, 32, 0, (K2), CB);                                                    \
        asm volatile("s_waitcnt lgkmcnt(0)" ::: "memory");                             \
        __builtin_amdgcn_s_setprio(1);                                                 \
        MFMA_Q(1, 0, a, b0);                                                           \
        __builtin_amdgcn_s_setprio(0);                                                 \
        BAR();                                                                         \
        STAGE(PA2, 64, 1, (K2), CA);                                                   \
        __builtin_amdgcn_s_setprio(1);                                                 \
        MFMA_Q(1, 1, a, b1);                                                           \
        __builtin_amdgcn_s_setprio(0);                                                 \
        asm volatile("s_waitcnt vmcnt(6)" ::: "memory");                               \
        BAR();                                                                         \
    }

__device__ __forceinline__ float fsig(float x) { return 1.f / (1.f + __expf(-x)); }
__device__ __forceinline__ float ftanh(float x) {
    x = fminf(fmaxf(x, -15.f), 15.f);
    float e = __expf(2.f * x);
    return (e - 1.f) / (e + 1.f);
}

__global__ __launch_bounds__(512, 2) void gemm8_k(
    const __hip_bfloat16* __restrict__ A,   // comb [8192][4096]
    const __hip_bfloat16* __restrict__ BT,  // WT   [8192][4096] (gate-interleaved rows)
    const float* __restrict__ cell,         // [8192][2048]
    const float* __restrict__ bfb, const float* __restrict__ bcb,
    const float* __restrict__ bib, const float* __restrict__ bob,
    float* __restrict__ out)                // [out | hid | cst], each [8192][2048]
{
    extern __shared__ char smem[];

    const int tid  = threadIdx.x;
    const int wave = tid >> 6;
    const int lane = tid & 63;
    const int wr = wave >> 2;   // 0..1
    const int wc = wave & 3;    // 0..3
    const int fr = lane & 15;
    const int sw0 = (((lane >> 4) + 0) ^ (fr & 7)) << 4;
    const int sw1 = (((lane >> 4) + 4) ^ (fr & 7)) << 4;

    // persistent mapping: fixed n-column per block, 4 m-works
    const int r0   = tid >> 3;
    const int col0 = ((tid & 7) ^ (r0 & 7)) << 3;
    const __hip_bfloat16* pB =
        BT + (size_t)((blockIdx.x >> 3) * 256 + ((r0 >> 5) << 6) + (r0 & 31)) * D_SZ + col0;
    const __hip_bfloat16* pA =
        A + (size_t)((blockIdx.x & 7) * 1024 + r0) * D_SZ + col0;   // work it=0

    f32x4 acc[8][4] = {};
    bf16x8 a[4][2], b0[2][2], b1[2][2];

    // prologue: tile0 -> buf0, tile1 A0,B0,A1 -> buf1 (invariant established)
    STAGE(pA, 64, 0, 0, 0);
    STAGE(pB, 32, 0, 0, 32768);
    STAGE(pA, 64, 1, 0, 0);
    STAGE(pB, 32, 1, 0, 32768);
    STAGE(pA, 64, 0, 1, 65536);
    STAGE(pB, 32, 0, 1, 98304);
    STAGE(pA, 64, 1, 1, 65536);
    asm volatile("s_waitcnt vmcnt(6)" ::: "memory");
    BAR();

#pragma unroll 1
    for (int it = 0; it < 4; ++it) {
        // steady tiles 0..61 (no wrap inside)
#pragma unroll 1
        for (int t = 0; t < 62; t += 2) {
            TILE_FULL(0,     32768, 98304, pA, t + 1, t + 2);
            TILE_FULL(65536, 98304, 32768, pA, t + 2, t + 3);
        }
        // boundary tiles 62,63: stage next work's tiles 0,1 (it=3 wraps into
        // the WT workspace region — valid memory, data unused)
        TILE_FULL(0,     32768, 98304, pA + ANX, 63, 0);
        TILE_FULL(65536, 98304, 32768, pA + ANX, 0, 1);

        // ---- fused LSTM epilogue for work `it` (all state scoped here so the
        // K-loop's register live-set stays under the 256/wave cap)
        {
            const int crow = (lane >> 4) * 4;
            const int ccol = lane & 15;
            const int hh = ((blockIdx.x >> 3) * 4 + wc) * 16 + ccol;
            const float bf_ = bfb[hh], bc_ = bcb[hh], bi_ = bib[hh], bo_ = bob[hh];
            const size_t BH = (size_t)B_SZ * H_SZ;
            float* hidp = out + BH;
            float* cstp = out + 2 * BH;
            const int m0w = ((blockIdx.x & 7) * 4 + it) * 256;
#pragma unroll
            for (int ai = 0; ai < 8; ++ai) {
#pragma unroll
                for (int j = 0; j < 4; ++j) {
                    const size_t r = (size_t)(m0w + wr * 128 + ai * 16 + crow + j);
                    const size_t idx = r * H_SZ + hh;
                    const float gf = acc[ai][0][j] + bf_;
                    const float gc = acc[ai][1][j] + bc_;
                    const float gi = acc[ai][2][j] + bi_;
                    const float go = acc[ai][3][j] + bo_;
                    const float ft = fsig(gf);
                    const float ct = ftanh(gc);
                    const float it_ = fsig(fsig(gi));   // double sigmoid, faithful
                    const float ot = fsig(go);
                    const float cv = __builtin_nontemporal_load(cell + idx);
                    const float cs = cv * ft + ct * it_;
                    __builtin_nontemporal_store(ot, out + idx);
                    __builtin_nontemporal_store(cs, cstp + idx);
                    __builtin_nontemporal_store(ot * ftanh(cs), hidp + idx);
                }
            }
        }
        // reset accumulators (unconditional — last one is harmless)
#pragma unroll
        for (int ai = 0; ai < 8; ++ai)
#pragma unroll
            for (int bj = 0; bj < 4; ++bj)
                acc[ai][bj] = (f32x4){0.f, 0.f, 0.f, 0.f};
        pA += ANX;
    }

    // drain pending LDS-DMA (wrap prefetch of the last work) before endpgm
    asm volatile("s_waitcnt vmcnt(0)" ::: "memory");
}

// ---------------------------------------------------------------------------
extern "C" void kernel_launch(void* const* d_in, const int* in_sizes, int n_in,
                              void* d_out, int out_size, void* d_ws, size_t ws_size,
                              hipStream_t stream) {
    const float* input  = (const float*)d_in[0];
    const float* hidden = (const float*)d_in[1];
    const float* cell   = (const float*)d_in[2];
    const float* Wf     = (const float*)d_in[3];
    const float* bfb    = (const float*)d_in[4];
    const float* Wc     = (const float*)d_in[5];
    const float* bcb    = (const float*)d_in[6];
    const float* Wi     = (const float*)d_in[7];
    const float* bib    = (const float*)d_in[8];
    const float* Wo     = (const float*)d_in[9];
    const float* bob    = (const float*)d_in[10];
    float* out = (float*)d_out;

    char* ws = (char*)d_ws;
    __hip_bfloat16* comb = (__hip_bfloat16*)ws;                              // 64 MiB
    __hip_bfloat16* WT   = (__hip_bfloat16*)(ws + (size_t)B_SZ * D_SZ * 2);  // 64 MiB

    hipFuncSetAttribute(reinterpret_cast<const void*>(gemm8_k),
                        hipFuncAttributeMaxDynamicSharedMemorySize, 131072);

    prep_k<<<2048 + 32768, 256, 0, stream>>>(input, hidden, comb, Wf, Wc, Wi, Wo, WT);
    gemm8_k<<<256, 512, 131072, stream>>>(comb, WT, cell, bfb, bcb, bib, bob, out);
}